// Round 5
// baseline (946.339 us; speedup 1.0000x reference)
//
#include <hip/hip_runtime.h>
#include <stdint.h>

// ---------------- types / helpers ----------------
typedef __bf16 bf16x8 __attribute__((ext_vector_type(8)));
typedef float f32x4 __attribute__((ext_vector_type(4)));
typedef unsigned short u16x8 __attribute__((ext_vector_type(8)));
typedef unsigned short u16x4 __attribute__((ext_vector_type(4)));

#define MFMA16(a, b, c) __builtin_amdgcn_mfma_f32_16x16x32_bf16(a, b, c, 0, 0, 0)
#define BAR() __builtin_amdgcn_s_barrier()
#define LGK0() do { asm volatile("s_waitcnt lgkmcnt(0)" ::: "memory"); \
                    __builtin_amdgcn_sched_barrier(0); } while (0)
#define VMC(n) asm volatile("s_waitcnt vmcnt(" #n ")" ::: "memory")
#define PRIO(p) __builtin_amdgcn_s_setprio(p)

#define TSEQ 8192
#define BATCH 4

static __device__ __forceinline__ unsigned short f2bf(float f) {
  union { float f; unsigned u; } v; v.f = f;
  unsigned u = v.u + 0x7FFFu + ((v.u >> 16) & 1u); // RNE
  return (unsigned short)(u >> 16);
}
static __device__ __forceinline__ float bf2f(unsigned short h) {
  union { unsigned u; float f; } v; v.u = ((unsigned)h) << 16; return v.f;
}
static __device__ __forceinline__ void gload16(const void* g, void* l) {
  __builtin_amdgcn_global_load_lds((const __attribute__((address_space(1))) void*)g,
                                   (__attribute__((address_space(3))) void*)l, 16, 0, 0);
}

// ---------------- K0: f32 -> bf16 convert ----------------
__global__ __launch_bounds__(256) void cvt_bf16(const float* __restrict__ s,
                                                unsigned short* __restrict__ d, int n) {
  int i = (blockIdx.x * 256 + threadIdx.x) * 8;
  if (i >= n) return;
  const float4 a = *(const float4*)(s + i);
  const float4 b = *(const float4*)(s + i + 4);
  u16x8 o;
  o[0] = f2bf(a.x); o[1] = f2bf(a.y); o[2] = f2bf(a.z); o[3] = f2bf(a.w);
  o[4] = f2bf(b.x); o[5] = f2bf(b.y); o[6] = f2bf(b.z); o[7] = f2bf(b.w);
  *(u16x8*)(d + i) = o;
}

// fused weight convert: Wq,Wk,Wv -> wcat, Wo -> wobf. grid 2048, region = bid>>9.
__global__ __launch_bounds__(256) void cvt_weights(const float* __restrict__ wq,
                                                   const float* __restrict__ wk,
                                                   const float* __restrict__ wv,
                                                   const float* __restrict__ wo,
                                                   unsigned short* __restrict__ wcat,
                                                   unsigned short* __restrict__ wobf) {
  const int r = blockIdx.x >> 9;
  const float* s = (r == 0) ? wq : (r == 1) ? wk : (r == 2) ? wv : wo;
  unsigned short* d = (r < 3) ? (wcat + r * 1048576) : wobf;
  const int i = ((blockIdx.x & 511) * 256 + threadIdx.x) * 8;
  const float4 a = *(const float4*)(s + i);
  const float4 b = *(const float4*)(s + i + 4);
  u16x8 o;
  o[0] = f2bf(a.x); o[1] = f2bf(a.y); o[2] = f2bf(a.z); o[3] = f2bf(a.w);
  o[4] = f2bf(b.x); o[5] = f2bf(b.y); o[6] = f2bf(b.z); o[7] = f2bf(b.w);
  *(u16x8*)(d + i) = o;
}

// ================ 256x256 8-wave, BK=64, read/MFMA-overlapped GEMM core ========
// A: [M,1024] K-major bf16, B: [N,1024] K-major bf16 (B^T layout). 16 K-tiles.
// LDS: As/Bs = 2 bufs x 256 rows x 128 B = 64 KB each (128 KB static total).
// Row = 8 chunks of 16 B; involutive swizzle cp = c ^ (row&7) applied on the
// gload SOURCE (linear LDS dest) and on the ds_read side (0 conflicts, R1/R4).
// Waves 2M x 4N, wave-tile 128x64. Frags are read ONE PHASE AHEAD of use so the
// LDS drain overlaps the MFMA pipe; compiler inserts counted lgkm waits at use.
// Per tile t (5 barriers):
//  ph1: read b1(4)            | stage (t+1).A.h1 | q00(a0,b0 regs) | BAR
//  ph2: read a1(8)            |                  | q01(a0,b1)      | BAR
//  ph3:                       | stage (t+2).B    | q11(a1,b1)      | BAR
//  ph4: stage (t+2).A.h0 | VMC(6) | BAR | read next a0,b0(12) | q10(a1,b0)
//       | LGK0 | BAR
// Stage-safety: every staged region's last reads drained >=1 barrier earlier
// (b-reads drain at their use-wait one phase later; ph4 reads drain at LGK0).
// vmcnt(6) at ph4 leaves exactly (t+2).B(4)+(t+2).A.h0(2) outstanding ->
// tile t+1 fully landed before its post-BAR reads. Next-b0 is loaded into the
// dead b1 register set; callers ping-pong the two b-arrays across tile parity.

static __device__ __forceinline__ void stage_half(const unsigned short* __restrict__ G,
                                                  int grow0, char* L, int t, int h,
                                                  int tid, int w) {
  #pragma unroll
  for (int j = 0; j < 2; ++j) {
    const int ci = j * 512 + tid;
    const int rr = ci >> 3;                 // 0..127 within half
    const int gch = (ci & 7) ^ (rr & 7);    // pre-swizzled source chunk
    gload16(G + (size_t)(grow0 + h * 128 + rr) * 1024 + t * 64 + gch * 8,
            L + (t & 1) * 32768 + h * 16384 + j * 8192 + w * 1024);
  }
}

template <bool S1, bool S3, bool S4, int VM, bool RD>
static __device__ __forceinline__ void tile_body(
    const unsigned short* __restrict__ A, const unsigned short* __restrict__ B,
    int rowA0, int rowB0, char* As, char* Bs, int t, f32x4 acc[8][4],
    bf16x8 (&a0)[4][2], bf16x8 (&b0)[2][2], bf16x8 (&b1)[2][2],
    int Abase, int Bbase, int tid, int w) {
  const int buf = (t & 1) * 32768;
  const int nbuf = 32768 - buf;
  bf16x8 a1[4][2];
  // ---- ph1: read b1 | stage (t+1).A.h1 | q00 | BAR
  #pragma unroll
  for (int nf = 0; nf < 2; ++nf)
    #pragma unroll
    for (int ks = 0; ks < 2; ++ks)
      b1[nf][ks] = *(const bf16x8*)(Bs + ((buf + Bbase + (nf + 2) * 2048) ^ (ks << 6)));
  if (S1) stage_half(A, rowA0, As, t + 1, 1, tid, w);
  PRIO(1);
  #pragma unroll
  for (int mf = 0; mf < 4; ++mf)
    #pragma unroll
    for (int nf = 0; nf < 2; ++nf)
      #pragma unroll
      for (int ks = 0; ks < 2; ++ks)
        acc[mf][nf] = MFMA16(a0[mf][ks], b0[nf][ks], acc[mf][nf]);
  PRIO(0);
  BAR();
  // ---- ph2: read a1 | q01 | BAR
  #pragma unroll
  for (int mf = 0; mf < 4; ++mf)
    #pragma unroll
    for (int ks = 0; ks < 2; ++ks)
      a1[mf][ks] = *(const bf16x8*)(As + ((buf + Abase + (mf + 4) * 2048) ^ (ks << 6)));
  PRIO(1);
  #pragma unroll
  for (int mf = 0; mf < 4; ++mf)
    #pragma unroll
    for (int nf = 0; nf < 2; ++nf)
      #pragma unroll
      for (int ks = 0; ks < 2; ++ks)
        acc[mf][nf + 2] = MFMA16(a0[mf][ks], b1[nf][ks], acc[mf][nf + 2]);
  PRIO(0);
  BAR();
  // ---- ph3: stage (t+2).B | q11 | BAR
  if (S3) {
    stage_half(B, rowB0, Bs, t + 2, 0, tid, w);
    stage_half(B, rowB0, Bs, t + 2, 1, tid, w);
  }
  PRIO(1);
  #pragma unroll
  for (int mf = 0; mf < 4; ++mf)
    #pragma unroll
    for (int nf = 0; nf < 2; ++nf)
      #pragma unroll
      for (int ks = 0; ks < 2; ++ks)
        acc[mf + 4][nf + 2] = MFMA16(a1[mf][ks], b1[nf][ks], acc[mf + 4][nf + 2]);
  PRIO(0);
  BAR();
  // ---- ph4: stage (t+2).A.h0 | VMC | BAR | read next a0,b0 | q10 | LGK0 | BAR
  if (S4) stage_half(A, rowA0, As, t + 2, 0, tid, w);
  if (VM == 6) { VMC(6); } else if (VM == 0) { VMC(0); }
  if (VM >= 0) BAR();
  if (RD) {
    #pragma unroll
    for (int mf = 0; mf < 4; ++mf)
      #pragma unroll
      for (int ks = 0; ks < 2; ++ks)
        a0[mf][ks] = *(const bf16x8*)(As + ((nbuf + Abase + mf * 2048) ^ (ks << 6)));
    #pragma unroll
    for (int nf = 0; nf < 2; ++nf)
      #pragma unroll
      for (int ks = 0; ks < 2; ++ks)
        b1[nf][ks] = *(const bf16x8*)(Bs + ((nbuf + Bbase + nf * 2048) ^ (ks << 6)));
  }
  PRIO(1);
  #pragma unroll
  for (int mf = 0; mf < 4; ++mf)
    #pragma unroll
    for (int nf = 0; nf < 2; ++nf)
      #pragma unroll
      for (int ks = 0; ks < 2; ++ks)
        acc[mf + 4][nf] = MFMA16(a1[mf][ks], b0[nf][ks], acc[mf + 4][nf]);
  PRIO(0);
  if (RD) LGK0();
  BAR();
}

static __device__ __forceinline__ void gemm256(const unsigned short* __restrict__ A,
                                               const unsigned short* __restrict__ B,
                                               int rowA0, int rowB0,
                                               char* As, char* Bs, f32x4 acc[8][4]) {
  const int tid = threadIdx.x, l = tid & 63, w = tid >> 6;
  const int wr = w >> 2, wc = w & 3;
  const int cp0 = (l >> 4) ^ (l & 7);
  const int Abase = (wr * 128 + (l & 15)) * 128 + cp0 * 16;
  const int Bbase = (wc * 64 + (l & 15)) * 128 + cp0 * 16;
  bf16x8 a0[4][2], bX[2][2], bY[2][2];
  // prologue: T0 complete; T1.B + T1.A.h0 in flight (6 outstanding)
  stage_half(A, rowA0, As, 0, 0, tid, w);
  stage_half(A, rowA0, As, 0, 1, tid, w);
  stage_half(B, rowB0, Bs, 0, 0, tid, w);
  stage_half(B, rowB0, Bs, 0, 1, tid, w);
  stage_half(B, rowB0, Bs, 1, 0, tid, w);
  stage_half(B, rowB0, Bs, 1, 1, tid, w);
  stage_half(A, rowA0, As, 1, 0, tid, w);
  VMC(6); BAR();
  #pragma unroll
  for (int mf = 0; mf < 4; ++mf)
    #pragma unroll
    for (int ks = 0; ks < 2; ++ks)
      a0[mf][ks] = *(const bf16x8*)(As + ((Abase + mf * 2048) ^ (ks << 6)));
  #pragma unroll
  for (int nf = 0; nf < 2; ++nf)
    #pragma unroll
    for (int ks = 0; ks < 2; ++ks)
      bX[nf][ks] = *(const bf16x8*)(Bs + ((Bbase + nf * 2048) ^ (ks << 6)));
  #pragma unroll 1
  for (int i = 0; i < 7; ++i) {
    tile_body<true, true, true, 6, true>(A, B, rowA0, rowB0, As, Bs, 2 * i, acc,
                                         a0, bX, bY, Abase, Bbase, tid, w);
    tile_body<true, true, true, 6, true>(A, B, rowA0, rowB0, As, Bs, 2 * i + 1, acc,
                                         a0, bY, bX, Abase, Bbase, tid, w);
  }
  tile_body<true, false, false, 0, true>(A, B, rowA0, rowB0, As, Bs, 14, acc,
                                         a0, bX, bY, Abase, Bbase, tid, w);
  tile_body<false, false, false, -1, false>(A, B, rowA0, rowB0, As, Bs, 15, acc,
                                            a0, bY, bX, Abase, Bbase, tid, w);
}

// ---------------- K1: fused QKV GEMM + bias + feature map (256^2 tiles) ------
// grid 1536 = 128 Mtiles x 12 Ntiles. Ntile region: 0-3 q, 4-7 k, 8-11 v.
__global__ __launch_bounds__(512, 2) void qkv_gemm256(
    const unsigned short* __restrict__ xbf, const unsigned short* __restrict__ wcat,
    const float* __restrict__ bq, const float* __restrict__ bk, const float* __restrict__ bv,
    unsigned short* __restrict__ qout, unsigned short* __restrict__ kout,
    unsigned short* __restrict__ vout) {
  __shared__ char smem[131072]; // static 128 KiB (As 64K | Bs 64K)
  char* As = smem;
  char* Bs = smem + 65536;
  const int swz = (blockIdx.x & 7) * 192 + (blockIdx.x >> 3); // bijective, 1536%8==0
  const int mt = swz / 12, nt = swz % 12;
  f32x4 acc[8][4] = {};
  gemm256(xbf, wcat, mt * 256, nt * 256, As, Bs, acc);

  const int l = threadIdx.x & 63, w = threadIdx.x >> 6;
  const int wr = w >> 2, wc = w & 3;
  const int region = nt >> 2;
  const float* bias = (region == 0) ? bq : (region == 1) ? bk : bv;
  unsigned short* dst = (region == 0) ? qout : (region == 1) ? kout : vout;
  const int colb = (nt & 3) * 256 + wc * 64;
  #pragma unroll
  for (int mf = 0; mf < 8; ++mf) {
    #pragma unroll
    for (int nf = 0; nf < 4; ++nf) {
      const int col = colb + nf * 16 + (l & 15);
      const float bb = bias[col];
      #pragma unroll
      for (int j = 0; j < 4; ++j) {
        const int row = mt * 256 + wr * 128 + mf * 16 + (l >> 4) * 4 + j;
        float v = acc[mf][nf][j] + bb;
        if (region < 2) v = (v > 0.f) ? (v + 1.f) : __expf(v); // elu(x)+1
        dst[(size_t)row * 1024 + col] = f2bf(v);
      }
    }
  }
}

// ---------------- K4: output GEMM + bo, fp32 out (256^2 tiles) ----------------
__global__ __launch_bounds__(512, 2) void o_gemm256(
    const unsigned short* __restrict__ attn, const unsigned short* __restrict__ wo,
    const float* __restrict__ bo, float* __restrict__ out) {
  __shared__ char smem[131072]; // static 128 KiB (As 64K | Bs 64K)
  char* As = smem;
  char* Bs = smem + 65536;
  const int swz = (blockIdx.x & 7) * 64 + (blockIdx.x >> 3); // 512 blocks, 512%8==0
  const int mt = swz >> 2, nt = swz & 3;
  f32x4 acc[8][4] = {};
  gemm256(attn, wo, mt * 256, nt * 256, As, Bs, acc);

  const int l = threadIdx.x & 63, w = threadIdx.x >> 6;
  const int wr = w >> 2, wc = w & 3;
  #pragma unroll
  for (int mf = 0; mf < 8; ++mf) {
    #pragma unroll
    for (int nf = 0; nf < 4; ++nf) {
      const int col = nt * 256 + wc * 64 + nf * 16 + (l & 15);
      const float bb = bo[col];
      #pragma unroll
      for (int j = 0; j < 4; ++j) {
        const int row = mt * 256 + wr * 128 + mf * 16 + (l >> 4) * 4 + j;
        out[(size_t)row * 1024 + col] = acc[mf][nf][j] + bb;
      }
    }
  }
}

// ---------------- K2: kv partial reduce (fp32 vector) ----------------
// grid (64 bh, 64 tchunks) -> 16 waves/CU for latency hiding.
__global__ __launch_bounds__(64) void kv_reduce(const unsigned short* __restrict__ kbf,
                                                const unsigned short* __restrict__ vbf,
                                                float* __restrict__ part) {
  const int bh = blockIdx.x, tc = blockIdx.y;
  const int b = bh >> 4, h = bh & 15;
  const int l = threadIdx.x;
  const int tm = l & 15, td = l >> 4;
  const unsigned short* kb = kbf + (size_t)b * TSEQ * 1024 + h * 64;
  const unsigned short* vb = vbf + (size_t)b * TSEQ * 1024 + h * 64;
  float acc[4][16] = {};
  float ksum = 0.f;
  const int t0 = tc * 128;
  #pragma unroll 2
  for (int t = t0; t < t0 + 128; ++t) {
    const unsigned short* krow = kb + (size_t)t * 1024;
    const unsigned short* vrow = vb + (size_t)t * 1024;
    const u16x8 k8a = *(const u16x8*)(krow + td * 16);
    const u16x8 k8b = *(const u16x8*)(krow + td * 16 + 8);
    const u16x4 v4 = *(const u16x4*)(vrow + tm * 4);
    float kf[16];
    #pragma unroll
    for (int j = 0; j < 8; ++j) { kf[j] = bf2f(k8a[j]); kf[8 + j] = bf2f(k8b[j]); }
    float vf[4];
    #pragma unroll
    for (int i = 0; i < 4; ++i) vf[i] = bf2f(v4[i]);
    ksum += bf2f(krow[td * 16 + tm]);
    #pragma unroll
    for (int i = 0; i < 4; ++i)
      #pragma unroll
      for (int j = 0; j < 16; ++j)
        acc[i][j] += vf[i] * kf[j];
  }
  float* ps = part + (size_t)(tc * 64 + bh) * 65 * 64;
  #pragma unroll
  for (int i = 0; i < 4; ++i) {
    const int m = tm * 4 + i;
    #pragma unroll
    for (int j = 0; j < 16; j += 4) {
      float4 o = make_float4(acc[i][j], acc[i][j + 1], acc[i][j + 2], acc[i][j + 3]);
      *(float4*)(ps + m * 64 + td * 16 + j) = o;
    }
  }
  ps[64 * 64 + td * 16 + tm] = ksum; // row 64 = k_sum partial
}

// ---------------- K2b: reduce partials -> padded bf16 B-matrix [bh][80][64] ---
__global__ __launch_bounds__(256) void kv_finalize(const float* __restrict__ part,
                                                   unsigned short* __restrict__ bmat) {
  const int e = blockIdx.x * 256 + threadIdx.x;
  if (e >= 64 * 80 * 64) return;
  const int d = e & 63;
  const int r = (e >> 6) % 80;
  const int bh = e / (80 * 64);
  float s = 0.f;
  if (r < 65) {
    #pragma unroll
    for (int tc = 0; tc < 64; ++tc)
      s += part[((size_t)(tc * 64 + bh) * 65 + r) * 64 + d];
  }
  bmat[e] = f2bf(s); // rows 65..79 = 0 (MFMA padding)
}

// ---------------- K3: attn = (Q x Bmat^T) with on-the-fly normalization ------
__global__ __launch_bounds__(256) void attn_gemm(const unsigned short* __restrict__ qbf,
                                                 const unsigned short* __restrict__ bmat,
                                                 unsigned short* __restrict__ attn) {
  __shared__ char Qs[16384];  // 128 rows x 128B, chunk swizzle ^(r&7)
  __shared__ char Bs2[10240]; // 80 rows x 128B
  const int bh = blockIdx.x, mt = blockIdx.y;
  const int b = bh >> 4, h = bh & 15;
  const int tid = threadIdx.x, l = tid & 63, w = tid >> 6;

  const unsigned short* qbase = qbf + (size_t)(b * TSEQ + mt * 128) * 1024 + h * 64;
  #pragma unroll
  for (int r4 = 0; r4 < 4; ++r4) {
    const int ci = r4 * 256 + tid;
    const int row = ci >> 3;
    const int csrc = (ci & 7) ^ (row & 7);
    gload16(qbase + (size_t)row * 1024 + csrc * 8, Qs + (r4 * 256 + w * 64) * 16);
  }
  const unsigned short* bbase = bmat + (size_t)bh * 80 * 64;
  #pragma unroll
  for (int r4 = 0; r4 < 3; ++r4) {
    const int ci = r4 * 256 + tid;
    if (ci < 640) {
      const int row = ci >> 3;
      const int csrc = (ci & 7) ^ (row & 7);
      gload16(bbase + row * 64 + csrc * 8, Bs2 + (r4 * 256 + w * 64) * 16);
    }
  }
  __syncthreads();

  f32x4 acc[2][5] = {};
  #pragma unroll
  for (int ks = 0; ks < 2; ++ks) {
    bf16x8 af[2], bfr[5];
    #pragma unroll
    for (int m = 0; m < 2; ++m) {
      const int r = w * 32 + m * 16 + (l & 15);
      const int c = ((l >> 4) + ks * 4) ^ (r & 7);
      af[m] = *(const bf16x8*)(Qs + r * 128 + c * 16);
    }
    #pragma unroll
    for (int n = 0; n < 5; ++n) {
      const int r = n * 16 + (l & 15);
      const int c = ((l >> 4) + ks * 4) ^ (r & 7);
      bfr[n] = *(const bf16x8*)(Bs2 + r * 128 + c * 16);
    }
    #pragma unroll
    for (int m = 0; m < 2; ++m)
      #pragma unroll
      for (int n = 0; n < 5; ++n)
        acc[m][n] = MFMA16(af[m], bfr[n], acc[m][n]);
  }

  unsigned short* arow = attn + (size_t)(b * TSEQ + mt * 128) * 1024 + h * 64;
  #pragma unroll
  for (int m = 0; m < 2; ++m) {
    #pragma unroll
    for (int j = 0; j < 4; ++j) {
      const float den = __shfl(acc[m][4][j], (l & 48)); // col 64 = q . k_sum
      const float z = 1.f / (den + 1e-6f);
      const int row = w * 32 + m * 16 + (l >> 4) * 4 + j;
      #pragma unroll
      for (int n = 0; n < 4; ++n)
        arow[(size_t)row * 1024 + n * 16 + (l & 15)] = f2bf(acc[m][n][j] * z);
    }
  }
}

// ---------------- launch ----------------
extern "C" void kernel_launch(void* const* d_in, const int* in_sizes, int n_in,
                              void* d_out, int out_size, void* d_ws, size_t ws_size,
                              hipStream_t stream) {
  const float* x  = (const float*)d_in[0];
  const float* Wq = (const float*)d_in[1];
  const float* bq = (const float*)d_in[2];
  const float* Wk = (const float*)d_in[3];
  const float* bk = (const float*)d_in[4];
  const float* Wv = (const float*)d_in[5];
  const float* bv = (const float*)d_in[6];
  const float* Wo = (const float*)d_in[7];
  const float* bo = (const float*)d_in[8];
  float* out = (float*)d_out;
  char* ws = (char*)d_ws;

  unsigned short* xbf  = (unsigned short*)(ws + 0);          // 64 MB (dead after K1)
  unsigned short* wcat = (unsigned short*)(ws + 67108864);   // 6 MB (dead after K1)
  unsigned short* wobf = (unsigned short*)(ws + 73400320);   // 2 MB (live till K4)
  unsigned short* qbf  = (unsigned short*)(ws + 75497472);   // 64 MB
  unsigned short* kbf  = (unsigned short*)(ws + 142606336);  // 64 MB (attn reuses)
  unsigned short* vbf  = (unsigned short*)(ws + 209715200);  // 64 MB
  float* part          = (float*)(ws + 0);                   // 68 MB, in dead xbf+wcat
  unsigned short* bmat = (unsigned short*)(ws + 71303168);   // 0.65 MB, before wobf
  unsigned short* attn = kbf;                                // k dead after K2

  cvt_bf16<<<16384, 256, 0, stream>>>(x, xbf, 33554432);
  cvt_weights<<<2048, 256, 0, stream>>>(Wq, Wk, Wv, Wo, wcat, wobf);

  qkv_gemm256<<<1536, 512, 0, stream>>>(xbf, wcat, bq, bk, bv, qbf, kbf, vbf);
  kv_reduce<<<dim3(64, 64), 64, 0, stream>>>(kbf, vbf, part);
  kv_finalize<<<1280, 256, 0, stream>>>(part, bmat);
  attn_gemm<<<dim3(64, 64), 256, 0, stream>>>(qbf, bmat, attn);
  o_gemm256<<<512, 512, 0, stream>>>(attn, wobf, bo, out);
}

// Round 7
// 654.520 us; speedup vs baseline: 1.4459x; 1.4459x over previous
//
#include <hip/hip_runtime.h>
#include <stdint.h>

// ---------------- types / helpers ----------------
typedef __bf16 bf16x8 __attribute__((ext_vector_type(8)));
typedef float f32x4 __attribute__((ext_vector_type(4)));
typedef unsigned short u16x8 __attribute__((ext_vector_type(8)));
typedef unsigned short u16x4 __attribute__((ext_vector_type(4)));

#define MFMA16(a, b, c) __builtin_amdgcn_mfma_f32_16x16x32_bf16(a, b, c, 0, 0, 0)
#define BAR() __builtin_amdgcn_s_barrier()
// Plain counted-floor wait: loads cannot sink below (memory clobber), but the
// compiler may hoist MFMAs above and interleave its own counted lgkm waits
// (m201 form; NO sched_barrier wall — that was R4/R5's 39%-util mistake).
#define LGKP() asm volatile("s_waitcnt lgkmcnt(0)" ::: "memory")
#define VMC(n) asm volatile("s_waitcnt vmcnt(" #n ")" ::: "memory")
#define PRIO(p) __builtin_amdgcn_s_setprio(p)

#define TSEQ 8192
#define BATCH 4

static __device__ __forceinline__ unsigned short f2bf(float f) {
  union { float f; unsigned u; } v; v.f = f;
  unsigned u = v.u + 0x7FFFu + ((v.u >> 16) & 1u); // RNE
  return (unsigned short)(u >> 16);
}
static __device__ __forceinline__ float bf2f(unsigned short h) {
  union { unsigned u; float f; } v; v.u = ((unsigned)h) << 16; return v.f;
}
static __device__ __forceinline__ void gload16(const void* g, void* l) {
  __builtin_amdgcn_global_load_lds((const __attribute__((address_space(1))) void*)g,
                                   (__attribute__((address_space(3))) void*)l, 16, 0, 0);
}

// ---------------- K0: f32 -> bf16 convert ----------------
__global__ __launch_bounds__(256) void cvt_bf16(const float* __restrict__ s,
                                                unsigned short* __restrict__ d, int n) {
  int i = (blockIdx.x * 256 + threadIdx.x) * 8;
  if (i >= n) return;
  const float4 a = *(const float4*)(s + i);
  const float4 b = *(const float4*)(s + i + 4);
  u16x8 o;
  o[0] = f2bf(a.x); o[1] = f2bf(a.y); o[2] = f2bf(a.z); o[3] = f2bf(a.w);
  o[4] = f2bf(b.x); o[5] = f2bf(b.y); o[6] = f2bf(b.z); o[7] = f2bf(b.w);
  *(u16x8*)(d + i) = o;
}

// fused weight convert: Wq,Wk,Wv -> wcat, Wo -> wobf. grid 2048, region = bid>>9.
__global__ __launch_bounds__(256) void cvt_weights(const float* __restrict__ wq,
                                                   const float* __restrict__ wk,
                                                   const float* __restrict__ wv,
                                                   const float* __restrict__ wo,
                                                   unsigned short* __restrict__ wcat,
                                                   unsigned short* __restrict__ wobf) {
  const int r = blockIdx.x >> 9;
  const float* s = (r == 0) ? wq : (r == 1) ? wk : (r == 2) ? wv : wo;
  unsigned short* d = (r < 3) ? (wcat + r * 1048576) : wobf;
  const int i = ((blockIdx.x & 511) * 256 + threadIdx.x) * 8;
  const float4 a = *(const float4*)(s + i);
  const float4 b = *(const float4*)(s + i + 4);
  u16x8 o;
  o[0] = f2bf(a.x); o[1] = f2bf(a.y); o[2] = f2bf(a.z); o[3] = f2bf(a.w);
  o[4] = f2bf(b.x); o[5] = f2bf(b.y); o[6] = f2bf(b.z); o[7] = f2bf(b.w);
  *(u16x8*)(d + i) = o;
}

// ================ 256x256 8-wave, BK=64, m201-style 8-phase GEMM core ==========
// A: [M,1024] K-major bf16, B: [N,1024] K-major bf16 (B^T layout). 16 K-tiles.
// LDS: As/Bs = 2 bufs x 256 rows x 128 B = 64 KB each (128 KB static total).
// Row = 8 chunks of 16 B; involutive swizzle cp = c ^ (row&7) on gload SOURCE
// (linear LDS dest) and ds_read side (0 conflicts, verified R1/R4).
// Waves 2M x 4N, wave-tile 128x64. Per tile t, 4 phases (C-quadrants):
//  ph1: read a0(8)+b0(4) | stage (t+1).A.h1 | BAR lgk0 | q00 | BAR
//  ph2: read b1(4)       |                  | BAR lgk0 | q01 | BAR
//  ph3: read a1(8)       | stage (t+2).B    | BAR lgk0 | q11 | BAR
//  ph4:                  | stage (t+2).A.h0 | VMC(6) BAR | q10 | BAR
// lgk0 here is the PERMEABLE form (no sched_barrier): reads can't sink past it,
// MFMAs may hoist and start under the remaining LDS drain (compiler emits its
// own counted lgkmcnt for real deps — m97/m201-verified behavior).
// Stage-safety: each staged region's reads completed >=1 barrier earlier
// (every phase's ds_reads are consumed in-phase, so they are lgkm-complete
// before the phase-end BAR). vmcnt(6) at ph4 leaves exactly (t+2).B(4)+
// (t+2).A.h0(2) outstanding -> tile t+1 fully landed before its first reads.

static __device__ __forceinline__ void stage_half(const unsigned short* __restrict__ G,
                                                  int grow0, char* L, int t, int h,
                                                  int tid, int w) {
  #pragma unroll
  for (int j = 0; j < 2; ++j) {
    const int ci = j * 512 + tid;
    const int rr = ci >> 3;                 // 0..127 within half
    const int gch = (ci & 7) ^ (rr & 7);    // pre-swizzled source chunk
    gload16(G + (size_t)(grow0 + h * 128 + rr) * 1024 + t * 64 + gch * 8,
            L + (t & 1) * 32768 + h * 16384 + j * 8192 + w * 1024);
  }
}

template <bool S1, bool S3, bool S4, int VM>
static __device__ __forceinline__ void tile_body(
    const unsigned short* __restrict__ A, const unsigned short* __restrict__ B,
    int rowA0, int rowB0, char* As, char* Bs, int t, f32x4 acc[8][4],
    int Abase, int Bbase, int tid, int w) {
  const int buf = (t & 1) * 32768;
  bf16x8 a0[4][2], a1[4][2], b0[2][2], b1[2][2];
  // ---- ph1: q00
  #pragma unroll
  for (int mf = 0; mf < 4; ++mf)
    #pragma unroll
    for (int ks = 0; ks < 2; ++ks)
      a0[mf][ks] = *(const bf16x8*)(As + ((buf + Abase + mf * 2048) ^ (ks << 6)));
  #pragma unroll
  for (int nf = 0; nf < 2; ++nf)
    #pragma unroll
    for (int ks = 0; ks < 2; ++ks)
      b0[nf][ks] = *(const bf16x8*)(Bs + ((buf + Bbase + nf * 2048) ^ (ks << 6)));
  if (S1) stage_half(A, rowA0, As, t + 1, 1, tid, w);
  BAR(); LGKP(); PRIO(1);
  #pragma unroll
  for (int mf = 0; mf < 4; ++mf)
    #pragma unroll
    for (int nf = 0; nf < 2; ++nf)
      #pragma unroll
      for (int ks = 0; ks < 2; ++ks)
        acc[mf][nf] = MFMA16(a0[mf][ks], b0[nf][ks], acc[mf][nf]);
  PRIO(0); BAR();
  // ---- ph2: q01
  #pragma unroll
  for (int nf = 0; nf < 2; ++nf)
    #pragma unroll
    for (int ks = 0; ks < 2; ++ks)
      b1[nf][ks] = *(const bf16x8*)(Bs + ((buf + Bbase + (nf + 2) * 2048) ^ (ks << 6)));
  BAR(); LGKP(); PRIO(1);
  #pragma unroll
  for (int mf = 0; mf < 4; ++mf)
    #pragma unroll
    for (int nf = 0; nf < 2; ++nf)
      #pragma unroll
      for (int ks = 0; ks < 2; ++ks)
        acc[mf][nf + 2] = MFMA16(a0[mf][ks], b1[nf][ks], acc[mf][nf + 2]);
  PRIO(0); BAR();
  // ---- ph3: q11
  #pragma unroll
  for (int mf = 0; mf < 4; ++mf)
    #pragma unroll
    for (int ks = 0; ks < 2; ++ks)
      a1[mf][ks] = *(const bf16x8*)(As + ((buf + Abase + (mf + 4) * 2048) ^ (ks << 6)));
  if (S3) {
    stage_half(B, rowB0, Bs, t + 2, 0, tid, w);
    stage_half(B, rowB0, Bs, t + 2, 1, tid, w);
  }
  BAR(); LGKP(); PRIO(1);
  #pragma unroll
  for (int mf = 0; mf < 4; ++mf)
    #pragma unroll
    for (int nf = 0; nf < 2; ++nf)
      #pragma unroll
      for (int ks = 0; ks < 2; ++ks)
        acc[mf + 4][nf + 2] = MFMA16(a1[mf][ks], b1[nf][ks], acc[mf + 4][nf + 2]);
  PRIO(0); BAR();
  // ---- ph4: q10
  if (S4) stage_half(A, rowA0, As, t + 2, 0, tid, w);
  if (VM == 6) { VMC(6); } else { VMC(0); }
  BAR(); PRIO(1);
  #pragma unroll
  for (int mf = 0; mf < 4; ++mf)
    #pragma unroll
    for (int nf = 0; nf < 2; ++nf)
      #pragma unroll
      for (int ks = 0; ks < 2; ++ks)
        acc[mf + 4][nf] = MFMA16(a1[mf][ks], b0[nf][ks], acc[mf + 4][nf]);
  PRIO(0); BAR();
}

static __device__ __forceinline__ void gemm256(const unsigned short* __restrict__ A,
                                               const unsigned short* __restrict__ B,
                                               int rowA0, int rowB0,
                                               char* As, char* Bs, f32x4 acc[8][4]) {
  const int tid = threadIdx.x, l = tid & 63, w = tid >> 6;
  const int wr = w >> 2, wc = w & 3;
  const int cp0 = (l >> 4) ^ (l & 7);
  const int Abase = (wr * 128 + (l & 15)) * 128 + cp0 * 16;
  const int Bbase = (wc * 64 + (l & 15)) * 128 + cp0 * 16;
  // prologue: T0 complete; T1.B.h0,h1 + T1.A.h0 in flight (6 outstanding)
  stage_half(A, rowA0, As, 0, 0, tid, w);
  stage_half(A, rowA0, As, 0, 1, tid, w);
  stage_half(B, rowB0, Bs, 0, 0, tid, w);
  stage_half(B, rowB0, Bs, 0, 1, tid, w);
  stage_half(B, rowB0, Bs, 1, 0, tid, w);
  stage_half(B, rowB0, Bs, 1, 1, tid, w);
  stage_half(A, rowA0, As, 1, 0, tid, w);
  VMC(6); BAR();
  #pragma unroll 1
  for (int t = 0; t < 14; ++t)
    tile_body<true, true, true, 6>(A, B, rowA0, rowB0, As, Bs, t, acc, Abase, Bbase, tid, w);
  tile_body<true, false, false, 0>(A, B, rowA0, rowB0, As, Bs, 14, acc, Abase, Bbase, tid, w);
  tile_body<false, false, false, 0>(A, B, rowA0, rowB0, As, Bs, 15, acc, Abase, Bbase, tid, w);
}

// ---------------- K1: fused QKV GEMM + bias + feature map (256^2 tiles) ------
// grid 1536 = 128 Mtiles x 12 Ntiles. Ntile region: 0-3 q, 4-7 k, 8-11 v.
__global__ __launch_bounds__(512, 2) void qkv_gemm256(
    const unsigned short* __restrict__ xbf, const unsigned short* __restrict__ wcat,
    const float* __restrict__ bq, const float* __restrict__ bk, const float* __restrict__ bv,
    unsigned short* __restrict__ qout, unsigned short* __restrict__ kout,
    unsigned short* __restrict__ vout) {
  __shared__ char smem[131072]; // static 128 KiB (As 64K | Bs 64K)
  char* As = smem;
  char* Bs = smem + 65536;
  const int swz = (blockIdx.x & 7) * 192 + (blockIdx.x >> 3); // bijective, 1536%8==0
  const int mt = swz / 12, nt = swz % 12;
  f32x4 acc[8][4] = {};
  gemm256(xbf, wcat, mt * 256, nt * 256, As, Bs, acc);

  const int l = threadIdx.x & 63, w = threadIdx.x >> 6;
  const int wr = w >> 2, wc = w & 3;
  const int region = nt >> 2;
  const float* bias = (region == 0) ? bq : (region == 1) ? bk : bv;
  unsigned short* dst = (region == 0) ? qout : (region == 1) ? kout : vout;
  const int colb = (nt & 3) * 256 + wc * 64;
  #pragma unroll
  for (int mf = 0; mf < 8; ++mf) {
    #pragma unroll
    for (int nf = 0; nf < 4; ++nf) {
      const int col = colb + nf * 16 + (l & 15);
      const float bb = bias[col];
      #pragma unroll
      for (int j = 0; j < 4; ++j) {
        const int row = mt * 256 + wr * 128 + mf * 16 + (l >> 4) * 4 + j;
        float v = acc[mf][nf][j] + bb;
        if (region < 2) v = (v > 0.f) ? (v + 1.f) : __expf(v); // elu(x)+1
        dst[(size_t)row * 1024 + col] = f2bf(v);
      }
    }
  }
}

// ---------------- K4: output GEMM + bo, fp32 out (256^2 tiles) ----------------
__global__ __launch_bounds__(512, 2) void o_gemm256(
    const unsigned short* __restrict__ attn, const unsigned short* __restrict__ wo,
    const float* __restrict__ bo, float* __restrict__ out) {
  __shared__ char smem[131072]; // static 128 KiB (As 64K | Bs 64K)
  char* As = smem;
  char* Bs = smem + 65536;
  const int swz = (blockIdx.x & 7) * 64 + (blockIdx.x >> 3); // 512 blocks, 512%8==0
  const int mt = swz >> 2, nt = swz & 3;
  f32x4 acc[8][4] = {};
  gemm256(attn, wo, mt * 256, nt * 256, As, Bs, acc);

  const int l = threadIdx.x & 63, w = threadIdx.x >> 6;
  const int wr = w >> 2, wc = w & 3;
  #pragma unroll
  for (int mf = 0; mf < 8; ++mf) {
    #pragma unroll
    for (int nf = 0; nf < 4; ++nf) {
      const int col = nt * 256 + wc * 64 + nf * 16 + (l & 15);
      const float bb = bo[col];
      #pragma unroll
      for (int j = 0; j < 4; ++j) {
        const int row = mt * 256 + wr * 128 + mf * 16 + (l >> 4) * 4 + j;
        out[(size_t)row * 1024 + col] = acc[mf][nf][j] + bb;
      }
    }
  }
}

// ---------------- K2: kv partial reduce (fp32 vector) ----------------
// grid (64 bh, 64 tchunks) -> more waves/CU for latency hiding.
__global__ __launch_bounds__(64) void kv_reduce(const unsigned short* __restrict__ kbf,
                                                const unsigned short* __restrict__ vbf,
                                                float* __restrict__ part) {
  const int bh = blockIdx.x, tc = blockIdx.y;
  const int b = bh >> 4, h = bh & 15;
  const int l = threadIdx.x;
  const int tm = l & 15, td = l >> 4;
  const unsigned short* kb = kbf + (size_t)b * TSEQ * 1024 + h * 64;
  const unsigned short* vb = vbf + (size_t)b * TSEQ * 1024 + h * 64;
  float acc[4][16] = {};
  float ksum = 0.f;
  const int t0 = tc * 128;
  #pragma unroll 2
  for (int t = t0; t < t0 + 128; ++t) {
    const unsigned short* krow = kb + (size_t)t * 1024;
    const unsigned short* vrow = vb + (size_t)t * 1024;
    const u16x8 k8a = *(const u16x8*)(krow + td * 16);
    const u16x8 k8b = *(const u16x8*)(krow + td * 16 + 8);
    const u16x4 v4 = *(const u16x4*)(vrow + tm * 4);
    float kf[16];
    #pragma unroll
    for (int j = 0; j < 8; ++j) { kf[j] = bf2f(k8a[j]); kf[8 + j] = bf2f(k8b[j]); }
    float vf[4];
    #pragma unroll
    for (int i = 0; i < 4; ++i) vf[i] = bf2f(v4[i]);
    ksum += bf2f(krow[td * 16 + tm]);
    #pragma unroll
    for (int i = 0; i < 4; ++i)
      #pragma unroll
      for (int j = 0; j < 16; ++j)
        acc[i][j] += vf[i] * kf[j];
  }
  float* ps = part + (size_t)(tc * 64 + bh) * 65 * 64;
  #pragma unroll
  for (int i = 0; i < 4; ++i) {
    const int m = tm * 4 + i;
    #pragma unroll
    for (int j = 0; j < 16; j += 4) {
      float4 o = make_float4(acc[i][j], acc[i][j + 1], acc[i][j + 2], acc[i][j + 3]);
      *(float4*)(ps + m * 64 + td * 16 + j) = o;
    }
  }
  ps[64 * 64 + td * 16 + tm] = ksum; // row 64 = k_sum partial
}

// ---------------- K2b: reduce partials -> padded bf16 B-matrix [bh][80][64] ---
__global__ __launch_bounds__(256) void kv_finalize(const float* __restrict__ part,
                                                   unsigned short* __restrict__ bmat) {
  const int e = blockIdx.x * 256 + threadIdx.x;
  if (e >= 64 * 80 * 64) return;
  const int d = e & 63;
  const int r = (e >> 6) % 80;
  const int bh = e / (80 * 64);
  float s = 0.f;
  if (r < 65) {
    #pragma unroll
    for (int tc = 0; tc < 64; ++tc)
      s += part[((size_t)(tc * 64 + bh) * 65 + r) * 64 + d];
  }
  bmat[e] = f2bf(s); // rows 65..79 = 0 (MFMA padding)
}

// ---------------- K3: attn = (Q x Bmat^T) with on-the-fly normalization ------
__global__ __launch_bounds__(256) void attn_gemm(const unsigned short* __restrict__ qbf,
                                                 const unsigned short* __restrict__ bmat,
                                                 unsigned short* __restrict__ attn) {
  __shared__ char Qs[16384];  // 128 rows x 128B, chunk swizzle ^(r&7)
  __shared__ char Bs2[10240]; // 80 rows x 128B
  const int bh = blockIdx.x, mt = blockIdx.y;
  const int b = bh >> 4, h = bh & 15;
  const int tid = threadIdx.x, l = tid & 63, w = tid >> 6;

  const unsigned short* qbase = qbf + (size_t)(b * TSEQ + mt * 128) * 1024 + h * 64;
  #pragma unroll
  for (int r4 = 0; r4 < 4; ++r4) {
    const int ci = r4 * 256 + tid;
    const int row = ci >> 3;
    const int csrc = (ci & 7) ^ (row & 7);
    gload16(qbase + (size_t)row * 1024 + csrc * 8, Qs + (r4 * 256 + w * 64) * 16);
  }
  const unsigned short* bbase = bmat + (size_t)bh * 80 * 64;
  #pragma unroll
  for (int r4 = 0; r4 < 3; ++r4) {
    const int ci = r4 * 256 + tid;
    if (ci < 640) {
      const int row = ci >> 3;
      const int csrc = (ci & 7) ^ (row & 7);
      gload16(bbase + row * 64 + csrc * 8, Bs2 + (r4 * 256 + w * 64) * 16);
    }
  }
  __syncthreads();

  f32x4 acc[2][5] = {};
  #pragma unroll
  for (int ks = 0; ks < 2; ++ks) {
    bf16x8 af[2], bfr[5];
    #pragma unroll
    for (int m = 0; m < 2; ++m) {
      const int r = w * 32 + m * 16 + (l & 15);
      const int c = ((l >> 4) + ks * 4) ^ (r & 7);
      af[m] = *(const bf16x8*)(Qs + r * 128 + c * 16);
    }
    #pragma unroll
    for (int n = 0; n < 5; ++n) {
      const int r = n * 16 + (l & 15);
      const int c = ((l >> 4) + ks * 4) ^ (r & 7);
      bfr[n] = *(const bf16x8*)(Bs2 + r * 128 + c * 16);
    }
    #pragma unroll
    for (int m = 0; m < 2; ++m)
      #pragma unroll
      for (int n = 0; n < 5; ++n)
        acc[m][n] = MFMA16(af[m], bfr[n], acc[m][n]);
  }

  unsigned short* arow = attn + (size_t)(b * TSEQ + mt * 128) * 1024 + h * 64;
  #pragma unroll
  for (int m = 0; m < 2; ++m) {
    #pragma unroll
    for (int j = 0; j < 4; ++j) {
      const float den = __shfl(acc[m][4][j], (l & 48)); // col 64 = q . k_sum
      const float z = 1.f / (den + 1e-6f);
      const int row = w * 32 + m * 16 + (l >> 4) * 4 + j;
      #pragma unroll
      for (int n = 0; n < 4; ++n)
        arow[(size_t)row * 1024 + n * 16 + (l & 15)] = f2bf(acc[m][n][j] * z);
    }
  }
}

// ---------------- launch ----------------
extern "C" void kernel_launch(void* const* d_in, const int* in_sizes, int n_in,
                              void* d_out, int out_size, void* d_ws, size_t ws_size,
                              hipStream_t stream) {
  const float* x  = (const float*)d_in[0];
  const float* Wq = (const float*)d_in[1];
  const float* bq = (const float*)d_in[2];
  const float* Wk = (const float*)d_in[3];
  const float* bk = (const float*)d_in[4];
  const float* Wv = (const float*)d_in[5];
  const float* bv = (const float*)d_in[6];
  const float* Wo = (const float*)d_in[7];
  const float* bo = (const float*)d_in[8];
  float* out = (float*)d_out;
  char* ws = (char*)d_ws;

  unsigned short* xbf  = (unsigned short*)(ws + 0);          // 64 MB (dead after K1)
  unsigned short* wcat = (unsigned short*)(ws + 67108864);   // 6 MB (dead after K1)
  unsigned short* wobf = (unsigned short*)(ws + 73400320);   // 2 MB (live till K4)
  unsigned short* qbf  = (unsigned short*)(ws + 75497472);   // 64 MB
  unsigned short* kbf  = (unsigned short*)(ws + 142606336);  // 64 MB (attn reuses)
  unsigned short* vbf  = (unsigned short*)(ws + 209715200);  // 64 MB
  float* part          = (float*)(ws + 0);                   // 68 MB, in dead xbf+wcat
  unsigned short* bmat = (unsigned short*)(ws + 71303168);   // 0.65 MB, before wobf
  unsigned short* attn = kbf;                                // k dead after K2

  cvt_bf16<<<16384, 256, 0, stream>>>(x, xbf, 33554432);
  cvt_weights<<<2048, 256, 0, stream>>>(Wq, Wk, Wv, Wo, wcat, wobf);

  qkv_gemm256<<<1536, 512, 0, stream>>>(xbf, wcat, bq, bk, bv, qbf, kbf, vbf);
  kv_reduce<<<dim3(64, 64), 64, 0, stream>>>(kbf, vbf, part);
  kv_finalize<<<1280, 256, 0, stream>>>(part, bmat);
  attn_gemm<<<dim3(64, 64), 256, 0, stream>>>(qbf, bmat, attn);
  o_gemm256<<<512, 512, 0, stream>>>(attn, wobf, bo, out);
}